// Round 3
// baseline (1134.159 us; speedup 1.0000x reference)
//
#include <hip/hip_runtime.h>
#include <math.h>

// Problem constants (fixed by setup_inputs: B=8, n=256, s=256)
#define NCTRL 256          // control points
#define NA    259          // n + 3 (TPS system size)
#define NAUG  261          // + 2 rhs columns
#define APITCH 264         // padded row pitch (floats) for the augmented matrix
#define BATCH 8
#define SGRID 256
#define NB    32           // LU panel width
#define NPAN  9            // ceil(259/32): 8 full panels + 1 of width 3
#define SPITCH 232         // LDS stage pitch (>= max trailing cols 229)
#define PPITCH 36          // pan pitch (16B-aligned rows: 36*4=144)

// ---------------------------------------------------------------------------
// Kernel 1: build the augmented TPS system per batch.
// ---------------------------------------------------------------------------
__global__ __launch_bounds__(256) void build_kernel(const float* __restrict__ src,
                                                    const float* __restrict__ dst,
                                                    float* __restrict__ A){
  const int b = blockIdx.x;
  const float* sb = src + b*NCTRL*2;
  const float* db = dst + b*NCTRL*2;
  float* Ab = A + (size_t)b*NA*APITCH;
  __shared__ float sx[NCTRL], sy[NCTRL];
  {
    int t = threadIdx.x;
    sx[t] = sb[2*t]; sy[t] = sb[2*t+1];
  }
  __syncthreads();
  const int total = NA*APITCH;
  for (int idx = threadIdx.x; idx < total; idx += 256){
    int r = idx / APITCH;
    int c = idx - r*APITCH;
    float v = 0.0f;
    if (r < NCTRL){
      if (c < NCTRL){
        float dx = sx[r] - sx[c];
        float dy = sy[r] - sy[c];
        v = sqrtf(fmaf(dx, dx, dy*dy));
      } else if (c == NCTRL)   v = 1.0f;
      else if (c == NCTRL+1)   v = sx[r];
      else if (c == NCTRL+2)   v = sy[r];
      else if (c == NA)        v = db[2*r];
      else if (c == NA+1)      v = db[2*r+1];
    } else if (c < NCTRL){
      v = (r == NCTRL) ? 1.0f : ((r == NCTRL+1) ? sx[c] : sy[c]);
    }
    Ab[idx] = v;
  }
}

// ---------------------------------------------------------------------------
// Register-resident panel factorization: thread t owns panel row t in VGPRs.
// Fully unrolled over the NBC mini-steps (static rr[] indexing — rule #20).
// 2 barriers per mini-step; prow/jrow/redv are parity double-buffered so
// next-step writes can't race this step's reads.
// On exit: pan[t][0..NBC-1] holds the factored panel (L\U), U11 written back
// to global, pivloc[] filled.
// ---------------------------------------------------------------------------
template<int NBC>
__device__ __forceinline__ void panel_factor_regs(
    float* __restrict__ Ab, int k0, int rows, int tid, int lane, int wid,
    float (*pan)[PPITCH], int* pivloc,
    float (*prow)[40], float (*jrow)[40], float (*redv)[8], int (*redi)[8])
{
  float rr[NBC];
  if (tid < rows){
    const float* g = Ab + (size_t)(k0+tid)*APITCH + k0;
    if (NBC == NB){
      #pragma unroll
      for (int q = 0; q < NBC/4; ++q){
        float4 v = *(const float4*)(g + 4*q);
        rr[4*q]=v.x; rr[4*q+1]=v.y; rr[4*q+2]=v.z; rr[4*q+3]=v.w;
      }
    } else {
      #pragma unroll
      for (int c = 0; c < NBC; ++c) rr[c] = g[c];
    }
  }

  #pragma unroll
  for (int j = 0; j < NBC; ++j){
    const int par = j & 1;
    // --- pivot search: wave shfl-argmax on register values ---
    float bv = (tid >= j && tid < rows) ? fabsf(rr[j]) : -1.0f;
    int bi = tid;
    #pragma unroll
    for (int off = 32; off; off >>= 1){
      float ov = __shfl_xor(bv, off);
      int   oi = __shfl_xor(bi, off);
      if (ov > bv || (ov == bv && oi < bi)){ bv = ov; bi = oi; }
    }
    if (lane == 0){ redv[par][wid] = bv; redi[par][wid] = bi; }
    __syncthreads();                                   // B1
    bv = redv[par][0]; bi = redi[par][0];
    #pragma unroll
    for (int w = 1; w < 8; ++w){
      if (redv[par][w] > bv || (redv[par][w] == bv && redi[par][w] < bi)){
        bv = redv[par][w]; bi = redi[par][w];
      }
    }
    // --- stage pivot row (and displaced row j) in LDS ---
    if (tid == bi){
      #pragma unroll
      for (int c = 0; c < NBC; ++c) prow[par][c] = rr[c];
    }
    if (tid == j && j != bi){
      #pragma unroll
      for (int c = 0; c < NBC; ++c) jrow[par][c] = rr[c];
    }
    if (tid == 0) pivloc[j] = bi;
    __syncthreads();                                   // B2
    // --- register swap ---
    if (j != bi){
      if (tid == j){
        #pragma unroll
        for (int c = 0; c < NBC; ++c) rr[c] = prow[par][c];
      } else if (tid == bi){
        #pragma unroll
        for (int c = 0; c < NBC; ++c) rr[c] = jrow[par][c];
      }
    }
    // --- broadcast pivot row into registers (vector LDS reads) ---
    float pr[NBC];
    if (NBC == NB){
      #pragma unroll
      for (int q = 0; q < NBC/4; ++q){
        if (4*q + 3 >= j){
          float4 v = *(const float4*)&prow[par][4*q];
          pr[4*q]=v.x; pr[4*q+1]=v.y; pr[4*q+2]=v.z; pr[4*q+3]=v.w;
        }
      }
    } else {
      #pragma unroll
      for (int c = 0; c < NBC; ++c) if (c >= j) pr[c] = prow[par][c];
    }
    // --- rank-1 update, fully in registers ---
    if (tid > j && tid < rows){
      float f = rr[j] / pr[j];
      rr[j] = f;
      #pragma unroll
      for (int c = j+1; c < NBC; ++c) rr[c] = fmaf(-f, pr[c], rr[c]);
    }
  }

  // --- dump factored panel to LDS for TRSM/GEMM; write U11 back ---
  if (tid < rows){
    if (NBC == NB){
      #pragma unroll
      for (int q = 0; q < NBC/4; ++q){
        float4 v; v.x=rr[4*q]; v.y=rr[4*q+1]; v.z=rr[4*q+2]; v.w=rr[4*q+3];
        *(float4*)&pan[tid][4*q] = v;
        if (tid < NBC) *(float4*)(Ab + (size_t)(k0+tid)*APITCH + k0 + 4*q) = v;
      }
    } else {
      #pragma unroll
      for (int c = 0; c < NBC; ++c){
        pan[tid][c] = rr[c];
        if (tid < NBC) Ab[(size_t)(k0+tid)*APITCH + k0 + c] = rr[c];
      }
    }
  }
}

// ---------------------------------------------------------------------------
// Kernel 2: blocked right-looking LU with partial pivoting, one block/batch.
// ---------------------------------------------------------------------------
__global__ __launch_bounds__(512) void lu_blocked(float* __restrict__ A,
                                                  float* __restrict__ wv){
  const int b = blockIdx.x;
  float* Ab = A + (size_t)b*NA*APITCH;
  const int tid  = threadIdx.x;
  const int lane = tid & 63;
  const int wid  = tid >> 6;

  __shared__ float pan[NA][PPITCH];    // factored panel: 259*36*4 = 37.3 KB
  __shared__ float stg[2*NB][SPITCH];  // laswp stage + U12: 64*232*4 = 59.4 KB
  __shared__ float xs2[NA*2];
  __shared__ float tsum[NB][2];
  __shared__ int   perm[NA];
  __shared__ int   pivloc[NB];
  __shared__ int   mvlist[2*NB];
  __shared__ int   mvcnt;
  __shared__ float prow[2][40], jrow[2][40];
  __shared__ float redv[2][8];
  __shared__ int   redi[2][8];

  // ======================== factorization ========================
  for (int p = 0; p < NPAN; ++p){
    const int k0   = p*NB;
    const int nb   = (NA - k0 < NB) ? (NA - k0) : NB;
    const int rows = NA - k0;
    const int ctop = k0 + nb;          // first trailing column
    const int tc   = NAUG - ctop;      // trailing cols incl 2 rhs

    if (tid == 0) mvcnt = 0;
    __syncthreads();

    if (nb == NB)
      panel_factor_regs<NB>(Ab, k0, rows, tid, lane, wid, pan, pivloc, prow, jrow, redv, redi);
    else
      panel_factor_regs<3>(Ab, k0, rows, tid, lane, wid, pan, pivloc, prow, jrow, redv, redi);

    // --- compose row permutation of this panel ---
    for (int i = tid; i < rows; i += 512) perm[i] = i;
    __syncthreads();
    if (tid == 0){
      for (int j = 0; j < nb; ++j){
        int pj = pivloc[j];
        int t = perm[j]; perm[j] = perm[pj]; perm[pj] = t;
      }
    }
    __syncthreads();
    for (int i = tid; i < rows; i += 512)
      if (perm[i] != i){ int s = atomicAdd(&mvcnt, 1); mvlist[s] = i; }
    __syncthreads();

    // --- laswp: permute trailing cols of moved rows (gather via LDS) ---
    const int M = mvcnt;               // <= 64
    if (tc > 0 && M > 0){
      for (int idx = tid; idx < M*tc; idx += 512){
        int m = idx / tc, c = idx - m*tc;
        stg[m][c] = Ab[(size_t)(k0 + perm[mvlist[m]])*APITCH + ctop + c];
      }
      __syncthreads();
      for (int idx = tid; idx < M*tc; idx += 512){
        int m = idx / tc, c = idx - m*tc;
        Ab[(size_t)(k0 + mvlist[m])*APITCH + ctop + c] = stg[m][c];
      }
      __syncthreads();
    }

    // --- TRSM: U12 = L11^{-1} A12, thread-per-column, static unroll ---
    if (tc > 0){
      if (nb == NB){
        for (int c = tid; c < tc; c += 512){
          float u[NB];
          #pragma unroll
          for (int m = 0; m < NB; ++m) u[m] = Ab[(size_t)(k0+m)*APITCH + ctop + c];
          #pragma unroll
          for (int m = 0; m < NB; ++m){
            #pragma unroll
            for (int jj = m+1; jj < NB; ++jj)
              u[jj] = fmaf(-pan[jj][m], u[m], u[jj]);
          }
          #pragma unroll
          for (int m = 0; m < NB; ++m){
            Ab[(size_t)(k0+m)*APITCH + ctop + c] = u[m];
            stg[m][c] = u[m];
          }
        }
      } else {                         // nb == 3 tail panel
        for (int c = tid; c < tc; c += 512){
          float u0 = Ab[(size_t)(k0+0)*APITCH + ctop + c];
          float u1 = Ab[(size_t)(k0+1)*APITCH + ctop + c];
          float u2 = Ab[(size_t)(k0+2)*APITCH + ctop + c];
          u1 -= pan[1][0]*u0;
          u2 -= pan[2][0]*u0;
          u2 -= pan[2][1]*u1;
          Ab[(size_t)(k0+0)*APITCH + ctop + c] = u0;
          Ab[(size_t)(k0+1)*APITCH + ctop + c] = u1;
          Ab[(size_t)(k0+2)*APITCH + ctop + c] = u2;
        }
      }
      __syncthreads();
    }

    // --- GEMM: A22 -= L21 * U12, 4x4 register tiles ---
    const int R = rows - nb;
    if (R > 0 && tc > 0){
      const int rt = (R + 3) >> 2, ct = (tc + 3) >> 2;
      for (int t = tid; t < rt*ct; t += 512){
        int tr  = t / ct, tcc = t - tr*ct;
        int i0  = nb + tr*4;
        int c0  = tcc*4;
        float acc[4][4] = {};
        const bool full = (c0 + 4 <= tc);
        #pragma unroll
        for (int r = 0; r < 4; ++r){
          int i = i0 + r;
          if (i < rows){
            const float* g = Ab + (size_t)(k0+i)*APITCH + ctop + c0;
            if (full){
              float4 v = *(const float4*)g;
              acc[r][0]=v.x; acc[r][1]=v.y; acc[r][2]=v.z; acc[r][3]=v.w;
            } else {
              #pragma unroll
              for (int c = 0; c < 4; ++c)
                if (c0 + c < tc) acc[r][c] = g[c];
            }
          }
        }
        #pragma unroll
        for (int m = 0; m < NB; ++m){
          float4 uv = *(const float4*)&stg[m][c0];
          #pragma unroll
          for (int r = 0; r < 4; ++r){
            int ir = i0 + r; ir = (ir < rows) ? ir : (rows-1);
            float l = pan[ir][m];
            acc[r][0] = fmaf(-l, uv.x, acc[r][0]);
            acc[r][1] = fmaf(-l, uv.y, acc[r][1]);
            acc[r][2] = fmaf(-l, uv.z, acc[r][2]);
            acc[r][3] = fmaf(-l, uv.w, acc[r][3]);
          }
        }
        #pragma unroll
        for (int r = 0; r < 4; ++r){
          int i = i0 + r;
          if (i < rows){
            float* g = Ab + (size_t)(k0+i)*APITCH + ctop + c0;
            if (full){
              float4 v; v.x=acc[r][0]; v.y=acc[r][1]; v.z=acc[r][2]; v.w=acc[r][3];
              *(float4*)g = v;
            } else {
              #pragma unroll
              for (int c = 0; c < 4; ++c)
                if (c0 + c < tc) g[c] = acc[r][c];
            }
          }
        }
      }
      __syncthreads();
    }
  }

  // ======================== blocked back-substitution ========================
  for (int bp = NPAN-1; bp >= 0; --bp){
    const int k0 = bp*NB;
    const int nb = (NA - k0 < NB) ? (NA - k0) : NB;
    const int cs = k0 + nb;
    const int below = NA - cs;

    {
      int g = tid >> 3, sub = tid & 7;
      int row = g >> 1, ch = g & 1;
      float s = 0.0f;
      if (row < nb){
        const size_t rbase = (size_t)(k0+row)*APITCH;
        if (sub == 0) s = Ab[rbase + NA + ch];
        for (int c = sub; c < below; c += 8)
          s -= Ab[rbase + cs + c] * xs2[(cs + c)*2 + ch];
      }
      s += __shfl_xor(s, 4); s += __shfl_xor(s, 2); s += __shfl_xor(s, 1);
      if (row < nb && (sub == 0)) tsum[row][ch] = s;
    }
    for (int idx = tid; idx < nb*nb; idx += 512){
      int r = idx / nb, c = idx - r*nb;
      pan[r][c] = Ab[(size_t)(k0+r)*APITCH + k0 + c];
    }
    __syncthreads();
    if (wid == 0){
      int j = lane >> 1, ch = lane & 1;
      float tval = (j < nb) ? tsum[j][ch] : 0.0f;
      for (int k = nb-1; k >= 0; --k){
        float tk = __shfl(tval, 2*k + ch);
        float xk = tk / pan[k][k];
        if (j <  k) tval = fmaf(-pan[j][k], xk, tval);
        if (j == k) tval = xk;
      }
      if (j < nb) xs2[(k0+j)*2 + ch] = tval;
    }
    __syncthreads();
  }

  for (int i = tid; i < NA; i += 512){
    wv[((size_t)b*NA + i)*2 + 0] = xs2[i*2+0];
    wv[((size_t)b*NA + i)*2 + 1] = xs2[i*2+1];
  }
}

// ---------------------------------------------------------------------------
// Kernel 3: evaluate the warp on the s x s grid.
// ---------------------------------------------------------------------------
__global__ __launch_bounds__(256) void eval_kernel(const float* __restrict__ src,
                                                   const float* __restrict__ wv,
                                                   float* __restrict__ out){
  const int b  = blockIdx.x >> 8;
  const int yi = blockIdx.x & 255;
  const int xi = threadIdx.x;
  __shared__ float sx[NCTRL], sy[NCTRL], wx[NCTRL], wy[NCTRL];
  const float* sb = src + b*NCTRL*2;
  const float* wb = wv + (size_t)b*NA*2;
  sx[xi] = sb[2*xi]; sy[xi] = sb[2*xi+1];
  wx[xi] = wb[2*xi]; wy[xi] = wb[2*xi+1];
  __syncthreads();

  const float step = 2.0f/255.0f;
  const float gx = -1.0f + step*(float)xi;
  const float gy = -1.0f + step*(float)yi;

  float accx = wb[512] + wb[514]*gx + wb[516]*gy;
  float accy = wb[513] + wb[515]*gx + wb[517]*gy;

  #pragma unroll 8
  for (int j = 0; j < NCTRL; ++j){
    float dx = gx - sx[j];
    float dy = gy - sy[j];
    float r = sqrtf(fmaf(dx, dx, dy*dy));
    accx = fmaf(r, wx[j], accx);
    accy = fmaf(r, wy[j], accy);
  }
  out[((size_t)(b*2    )*SGRID + yi)*SGRID + xi] = accx;
  out[((size_t)(b*2 + 1)*SGRID + yi)*SGRID + xi] = accy;
}

// ---------------------------------------------------------------------------
extern "C" void kernel_launch(void* const* d_in, const int* in_sizes, int n_in,
                              void* d_out, int out_size, void* d_ws, size_t ws_size,
                              hipStream_t stream) {
  const float* src = (const float*)d_in[0];
  const float* dst = (const float*)d_in[1];
  float* out = (float*)d_out;

  const size_t matElems = (size_t)BATCH*NA*APITCH;
  float* A  = (float*)d_ws;
  float* wv = A + matElems;

  build_kernel<<<BATCH, 256, 0, stream>>>(src, dst, A);
  lu_blocked<<<BATCH, 512, 0, stream>>>(A, wv);
  eval_kernel<<<BATCH*SGRID, 256, 0, stream>>>(src, wv, out);
}